// Round 14
// baseline (768.418 us; speedup 1.0000x reference)
//
#include <hip/hip_runtime.h>

#define NN 50000
#define NE 800000
#define BN_EPS 1e-5f
#define SCAN_T 256
#define SCAN_NB ((NN + SCAN_T - 1) / SCAN_T) // 196

// bucketed CSR build
#define BKT_SH 8                    // 256 nodes per bucket
#define NBKT ((NN + 255) >> 8)      // 196
#define CAP 6144                    // stage capacity per bucket (mean 4096, sd 64)
#define PCH 4096                    // edges per partition block
#define NPB ((NE + PCH - 1) / PCH)  // 196

// stats layout: per-aggregation block of 320 floats; parent at 0, child at 320
#define ST_SUM1 0
#define ST_SQ1 64
#define ST_CROSS 128
#define ST_SUM2 192
#define ST_SSQ2 256
#define ST_AGG 320

using bf16x8 = __attribute__((ext_vector_type(8))) __bf16;
using bf16x4 = __attribute__((ext_vector_type(4))) __bf16;
using floatx4 = __attribute__((ext_vector_type(4))) float;

#define MFMA16(a, b, c) __builtin_amdgcn_mfma_f32_16x16x32_bf16(a, b, c, 0, 0, 0)

// W: row-major [K][ncols] f32. B-frag for 16x16x32: lane holds
// B[k = (lane>>4)*8 + j + kb*32][col = ct*16 + (lane&15)], j=0..7.
__device__ __forceinline__ bf16x8 load_wfrag(const float* W, int ncols, int kb, int ct, int lane) {
  int col = ct * 16 + (lane & 15);
  int k0 = kb * 32 + ((lane >> 4) << 3);
  bf16x8 f;
#pragma unroll
  for (int j = 0; j < 8; ++j) f[j] = (__bf16)W[(k0 + j) * ncols + col];
  return f;
}

// ---------------- setup ----------------
__global__ void k_setup(const int* __restrict__ nodes, const float* __restrict__ emb,
                        float* __restrict__ x, int* __restrict__ bcur) {
  int tid = blockIdx.x * blockDim.x + threadIdx.x;
  int stride = gridDim.x * blockDim.x;
  for (int idx = tid; idx < NN * 64; idx += stride)
    x[idx] = emb[nodes[idx >> 6] * 64 + (idx & 63)];
  for (int t = tid; t < 2 * NBKT; t += stride)
    bcur[t] = (t < NBKT ? t : t - NBKT) * CAP;
}

// Partition edges into node-buckets (256 nodes each). dir 0: key=dst (parent CSR),
// dir 1: key=src (child CSR). Payload packs (key<<16)|other.
__global__ void __launch_bounds__(256) k_part(const int* __restrict__ src,
                                              const int* __restrict__ dst,
                                              int* __restrict__ bcur,
                                              unsigned int* __restrict__ stage) {
  const int dir = blockIdx.y;
  const int* key = dir ? src : dst;
  int* bc = bcur + dir * NBKT;
  unsigned int* st = stage + (size_t)dir * NBKT * CAP;
  __shared__ int lh[256];
  __shared__ int sb[256];
  __shared__ int lbase[NBKT];
  __shared__ unsigned int pay[PCH];
  const int tid = threadIdx.x;
  lh[tid] = 0;
  __syncthreads();
  const int c0 = blockIdx.x * PCH;
  const int nv = (NE - c0 < PCH) ? (NE - c0) : PCH;
  unsigned int rk[PCH / 256];
#pragma unroll
  for (int i = 0; i < PCH / 256; ++i) {
    int l = i * 256 + tid;
    if (l < nv) {
      int b = key[c0 + l] >> BKT_SH;
      int r = atomicAdd(&lh[b], 1);
      rk[i] = ((unsigned)b << 13) | (unsigned)r;
    } else {
      rk[i] = 0xFFFFFFFFu;
    }
  }
  __syncthreads();
  int cntv = lh[tid];
  sb[tid] = cntv;
  __syncthreads();
  for (int o = 1; o < 256; o <<= 1) {
    int u = (tid >= o) ? sb[tid - o] : 0;
    __syncthreads();
    sb[tid] += u;
    __syncthreads();
  }
  int excl = sb[tid] - cntv;
  __syncthreads();
  sb[tid] = excl;
  if (tid < NBKT && cntv > 0) lbase[tid] = atomicAdd(&bc[tid], cntv);
  __syncthreads();
#pragma unroll
  for (int i = 0; i < PCH / 256; ++i) {
    if (rk[i] != 0xFFFFFFFFu) {
      int e = c0 + i * 256 + tid;
      int b = (int)(rk[i] >> 13);
      int r = (int)(rk[i] & 0x1FFFu);
      unsigned int s = (unsigned)src[e], d = (unsigned)dst[e];
      pay[sb[b] + r] = dir ? ((s << 16) | d) : ((d << 16) | s);
    }
  }
  __syncthreads();
  for (int t = tid; t < nv; t += 256) {
    int lo = 0, hi = 255;
    while (lo < hi) {
      int mid = (lo + hi + 1) >> 1;
      if (sb[mid] <= t) lo = mid; else hi = mid - 1;
    }
    st[lbase[lo] + (t - sb[lo])] = pay[t];
  }
}

__global__ void __launch_bounds__(256) k_count(const int* __restrict__ bcur,
                                               const unsigned int* __restrict__ stage,
                                               int* __restrict__ cnt_d, int* __restrict__ cnt_s) {
  const int dir = blockIdx.y;
  const int b = blockIdx.x;
  int* cnt = dir ? cnt_s : cnt_d;
  const unsigned int* st = stage + (size_t)dir * NBKT * CAP + (size_t)b * CAP;
  __shared__ int lc[256];
  lc[threadIdx.x] = 0;
  __syncthreads();
  int sz = bcur[dir * NBKT + b] - b * CAP;
  for (int t = threadIdx.x; t < sz; t += 256)
    atomicAdd(&lc[(st[t] >> 16) - (b << BKT_SH)], 1);
  __syncthreads();
  int n = (b << BKT_SH) + threadIdx.x;
  if (n < NN) cnt[n] = lc[threadIdx.x];
}

__global__ void k_scan1(const int* __restrict__ cnt_d, const int* __restrict__ cnt_s,
                        int* __restrict__ off_d, int* __restrict__ off_s, int* __restrict__ btot) {
  const int* cnt = blockIdx.y ? cnt_s : cnt_d;
  int* off = blockIdx.y ? off_s : off_d;
  __shared__ int sm[SCAN_T];
  int i = blockIdx.x * SCAN_T + threadIdx.x;
  int v = (i < NN) ? cnt[i] : 0;
  sm[threadIdx.x] = v;
  __syncthreads();
  for (int o = 1; o < SCAN_T; o <<= 1) {
    int u = (threadIdx.x >= o) ? sm[threadIdx.x - o] : 0;
    __syncthreads();
    sm[threadIdx.x] += u;
    __syncthreads();
  }
  if (i < NN) off[i] = sm[threadIdx.x];
  if (threadIdx.x == SCAN_T - 1) btot[blockIdx.y * SCAN_NB + blockIdx.x] = sm[SCAN_T - 1];
}

__global__ void k_scan2(int* __restrict__ btot) {
  __shared__ int sm[SCAN_T];
  int t = threadIdx.x;
  for (int y = 0; y < 2; ++y) {
    int v = (t < SCAN_NB) ? btot[y * SCAN_NB + t] : 0;
    sm[t] = v;
    __syncthreads();
    for (int o = 1; o < SCAN_T; o <<= 1) {
      int u = (t >= o) ? sm[t - o] : 0;
      __syncthreads();
      sm[t] += u;
      __syncthreads();
    }
    if (t < SCAN_NB) btot[y * SCAN_NB + t] = sm[t] - v;
    __syncthreads();
  }
}

__global__ void k_scan3(const int* __restrict__ cnt_d, const int* __restrict__ cnt_s,
                        int* __restrict__ off_d, int* __restrict__ off_s,
                        const int* __restrict__ btot, float* __restrict__ dinv_d,
                        float* __restrict__ dinv_s) {
  const int* cnt = blockIdx.y ? cnt_s : cnt_d;
  int* off = blockIdx.y ? off_s : off_d;
  float* dinv = blockIdx.y ? dinv_s : dinv_d;
  int i = blockIdx.x * SCAN_T + threadIdx.x;
  if (i < NN) {
    int incl = off[i];
    int c = cnt[i];
    int o = incl - c + btot[blockIdx.y * SCAN_NB + blockIdx.x];
    off[i] = o;
    dinv[i] = c > 0 ? 1.0f / (float)c : 0.f;
  }
  if (i == NN - 1) off[NN] = NE;
}

// Per-bucket CSR fill; also emits il (the i-node per CSR slot).
__global__ void __launch_bounds__(256) k_fill2(const int* __restrict__ bcur,
                                               const unsigned int* __restrict__ stage,
                                               const int* __restrict__ off_d,
                                               const int* __restrict__ off_s,
                                               unsigned short* __restrict__ jl_d,
                                               unsigned short* __restrict__ jl_s,
                                               unsigned short* __restrict__ il_d,
                                               unsigned short* __restrict__ il_s) {
  const int dir = blockIdx.y;
  const int b = blockIdx.x;
  const int* off = dir ? off_s : off_d;
  unsigned short* jl = dir ? jl_s : jl_d;
  unsigned short* il = dir ? il_s : il_d;
  const unsigned int* st = stage + (size_t)dir * NBKT * CAP + (size_t)b * CAP;
  __shared__ int lcur[256];
  __shared__ unsigned short ljl[CAP];
  __shared__ unsigned short lil[CAP];
  int csr0 = off[b << BKT_SH];
  int n = (b << BKT_SH) + threadIdx.x;
  lcur[threadIdx.x] = (n < NN) ? off[n] - csr0 : 0;
  __syncthreads();
  int sz = bcur[dir * NBKT + b] - b * CAP;
  for (int t = threadIdx.x; t < sz; t += 256) {
    unsigned int v = st[t];
    int p = atomicAdd(&lcur[(v >> 16) - (b << BKT_SH)], 1);
    ljl[p] = (unsigned short)(v & 0xFFFFu);
    lil[p] = (unsigned short)(v >> 16);
  }
  __syncthreads();
  for (int t = threadIdx.x; t < sz; t += 256) {
    jl[csr0 + t] = ljl[t];
    il[csr0 + t] = lil[t];
  }
}

// ---------------- per-iteration kernels ----------------
// KA (merged): blockIdx.y = 0 -> parent (pW1: A->iP lo, B->jP lo, do_zero),
//              blockIdx.y = 1 -> child  (cW1: A->jP hi, B->iP hi).
__global__ void __launch_bounds__(256) k_node_xform(
    const float* __restrict__ x, const float* __restrict__ pW1,
    const float* __restrict__ cW1, __bf16* __restrict__ iP, __bf16* __restrict__ jP,
    float* __restrict__ stats, int do_zero) {
  const int lane = threadIdx.x & 63;
  const int wid = threadIdx.x >> 6;
  const int yy = blockIdx.y;
  const float* W1 = yy ? cW1 : pW1;
  __bf16* Aout = yy ? (jP + 64) : iP;
  __bf16* Bout = yy ? (iP + 64) : jP;
  __shared__ alignas(16) __bf16 xb[4][16 * 72];
  if (do_zero && blockIdx.x == 0 && yy == 0)
    for (int t = threadIdx.x; t < 2 * ST_AGG; t += blockDim.x) stats[t] = 0.f;
  bf16x8 wfa[4][2], wfb[4][2];
#pragma unroll
  for (int ct = 0; ct < 4; ++ct)
#pragma unroll
    for (int kb = 0; kb < 2; ++kb) {
      wfa[ct][kb] = load_wfrag(W1, 64, kb, ct, lane);
      wfb[ct][kb] = load_wfrag(W1 + 64 * 64, 64, kb, ct, lane);
    }
  __bf16* vb = xb[wid];
  int wgid = (blockIdx.x * blockDim.x + threadIdx.x) >> 6;
  int nw = (gridDim.x * blockDim.x) >> 6;
  for (int tile = wgid; tile < NN / 16; tile += nw) {
#pragma unroll
    for (int t = 0; t < 16; ++t)
      vb[t * 72 + lane] = (__bf16)x[(tile * 16 + t) * 64 + lane];
    const bf16x8 a0 = *(const bf16x8*)&vb[(lane & 15) * 72 + ((lane >> 4) << 3)];
    const bf16x8 a1 = *(const bf16x8*)&vb[(lane & 15) * 72 + 32 + ((lane >> 4) << 3)];
#pragma unroll
    for (int ct = 0; ct < 4; ++ct) {
      floatx4 aA = {0.f, 0.f, 0.f, 0.f}, aB = {0.f, 0.f, 0.f, 0.f};
      aA = MFMA16(a0, wfa[ct][0], aA);
      aA = MFMA16(a1, wfa[ct][1], aA);
      aB = MFMA16(a0, wfb[ct][0], aB);
      aB = MFMA16(a1, wfb[ct][1], aB);
#pragma unroll
      for (int r = 0; r < 4; ++r) {
        int row = ((lane >> 4) << 2) + r;
        int n = tile * 16 + row;
        int col = ct * 16 + (lane & 15);
        Aout[(size_t)n * 128 + col] = (__bf16)aA[r];
        Bout[(size_t)n * 128 + col] = (__bf16)aB[r];
      }
    }
  }
}

// KB: degree-weighted node sums over interleaved iP/jP.
__global__ void __launch_bounds__(256) k_node_stats(
    const __bf16* __restrict__ iP, const __bf16* __restrict__ jP,
    const int* __restrict__ cnt_d, const int* __restrict__ cnt_s,
    float* __restrict__ stats) {
  const int lane = threadIdx.x & 63;
  const int g = lane >> 4, q = lane & 15;
  __shared__ float sacc[256];
  for (int t = threadIdx.x; t < 256; t += blockDim.x) sacc[t] = 0.f;
  __syncthreads();
  float sp[4] = {0, 0, 0, 0}, qp[4] = {0, 0, 0, 0};
  float sc[4] = {0, 0, 0, 0}, qc[4] = {0, 0, 0, 0};
  int wgid = (blockIdx.x * blockDim.x + threadIdx.x) >> 6;
  int nw = (gridDim.x * blockDim.x) >> 6;
  for (int ch = wgid; ch < NN / 4; ch += nw) {
    int n = ch * 4 + g;
    float wd = (float)cnt_d[n];
    float ws = (float)cnt_s[n];
    bf16x4 ap = *(const bf16x4*)(iP + (size_t)n * 128 + 4 * q);
    bf16x4 bp = *(const bf16x4*)(jP + (size_t)n * 128 + 4 * q);
    bf16x4 ac = *(const bf16x4*)(jP + (size_t)n * 128 + 64 + 4 * q);
    bf16x4 bc = *(const bf16x4*)(iP + (size_t)n * 128 + 64 + 4 * q);
#pragma unroll
    for (int k = 0; k < 4; ++k) {
      float a = (float)ap[k], b = (float)bp[k], c = (float)ac[k], d = (float)bc[k];
      sp[k] += wd * a + ws * b;
      qp[k] += wd * a * a + ws * b * b;
      sc[k] += ws * c + wd * d;
      qc[k] += ws * c * c + wd * d * d;
    }
  }
#pragma unroll
  for (int k = 0; k < 4; ++k) {
    sp[k] += __shfl_xor(sp[k], 16); sp[k] += __shfl_xor(sp[k], 32);
    qp[k] += __shfl_xor(qp[k], 16); qp[k] += __shfl_xor(qp[k], 32);
    sc[k] += __shfl_xor(sc[k], 16); sc[k] += __shfl_xor(sc[k], 32);
    qc[k] += __shfl_xor(qc[k], 16); qc[k] += __shfl_xor(qc[k], 32);
  }
  if (lane < 16) {
#pragma unroll
    for (int k = 0; k < 4; ++k) {
      atomicAdd(&sacc[4 * q + k], sp[k]);
      atomicAdd(&sacc[64 + 4 * q + k], qp[k]);
      atomicAdd(&sacc[128 + 4 * q + k], sc[k]);
      atomicAdd(&sacc[192 + 4 * q + k], qc[k]);
    }
  }
  __syncthreads();
  for (int t = threadIdx.x; t < 256; t += blockDim.x) {
    int dstoff = (t < 128) ? t : ST_AGG + (t - 128);
    atomicAdd(&stats[dstoff], sacc[t]);
  }
}

// KC v4: cross over dst-CSR positions with interleaved rows (verified R9 form).
__global__ void __launch_bounds__(256) k_cross_csr3(
    const unsigned short* __restrict__ il, const unsigned short* __restrict__ jl,
    const __bf16* __restrict__ iP, const __bf16* __restrict__ jP,
    float* __restrict__ stats) {
  const int lane = threadIdx.x & 63;
  const int c16 = lane & 15, r4 = lane >> 4;
  __shared__ float sacc[128];
  for (int t = threadIdx.x; t < 128; t += blockDim.x) sacc[t] = 0.f;
  __syncthreads();
  float acc[8] = {0, 0, 0, 0, 0, 0, 0, 0};
  int wgid = (blockIdx.x * blockDim.x + threadIdx.x) >> 6;
  int nw = (gridDim.x * blockDim.x) >> 6;
  for (int tile = wgid; tile < NE / 16; tile += nw) {
    int e0 = tile * 16;
    int iv = (int)il[e0 + c16];
    int jv = (int)jl[e0 + c16];
#pragma unroll
    for (int r = 0; r < 4; ++r) {
      int ee = r * 4 + r4;
      int i = __shfl(iv, ee);
      int j = __shfl(jv, ee);
      bf16x8 av = *(const bf16x8*)(iP + (size_t)i * 128 + c16 * 8);
      bf16x8 bv = *(const bf16x8*)(jP + (size_t)j * 128 + c16 * 8);
#pragma unroll
      for (int k = 0; k < 8; ++k) acc[k] += (float)av[k] * (float)bv[k];
    }
  }
#pragma unroll
  for (int k = 0; k < 8; ++k) {
    acc[k] += __shfl_xor(acc[k], 16);
    acc[k] += __shfl_xor(acc[k], 32);
  }
  if (lane < 16) {
#pragma unroll
    for (int k = 0; k < 8; ++k) {
      int dst = (c16 < 8) ? (c16 * 8 + k) : (64 + (c16 - 8) * 8 + k);
      atomicAdd(&sacc[dst], acc[k]);
    }
  }
  __syncthreads();
  for (int t = threadIdx.x; t < 128; t += blockDim.x) {
    int dstoff = (t < 64) ? (ST_CROSS + t) : (ST_AGG + ST_CROSS + (t - 64));
    atomicAdd(&stats[dstoff], sacc[t]);
  }
}

// KD v7: BN2 stats, wave-split by aggregation + 2-deep software pipeline
// (verified R13 form).
#define ES_ISSUE(iv, jv, r0a, r0b, r1a, r1b)                                   \
  {                                                                            \
    int i0 = __shfl((iv), e8), j0 = __shfl((jv), e8);                          \
    int i1 = __shfl((iv), 8 + e8), j1 = __shfl((jv), 8 + e8);                  \
    r0a = *(const bf16x8*)(iP + (size_t)i0 * 128 + halfoff + cbase);           \
    r0b = *(const bf16x8*)(jP + (size_t)j0 * 128 + halfoff + cbase);           \
    r1a = *(const bf16x8*)(iP + (size_t)i1 * 128 + halfoff + cbase);           \
    r1b = *(const bf16x8*)(jP + (size_t)j1 * 128 + halfoff + cbase);           \
  }
#define ES_COMPUTE(r0a, r0b, r1a, r1b)                                         \
  {                                                                            \
    bf16x8 v0, v1;                                                             \
    _Pragma("unroll") for (int k = 0; k < 8; ++k) {                            \
      v0[k] = (__bf16)fmaxf(s1[k] * ((float)r0a[k] + (float)r0b[k]) + t1[k], 0.f); \
      v1[k] = (__bf16)fmaxf(s1[k] * ((float)r1a[k] + (float)r1b[k]) + t1[k], 0.f); \
    }                                                                          \
    *(bf16x8*)&vb[e8 * 72 + cbase] = v0;                                       \
    *(bf16x8*)&vb[(8 + e8) * 72 + cbase] = v1;                                 \
    const bf16x8 a0 = *(const bf16x8*)&vb[q * 72 + g * 8];                     \
    const bf16x8 a1 = *(const bf16x8*)&vb[q * 72 + 32 + g * 8];                \
    _Pragma("unroll") for (int ct = 0; ct < 4; ++ct) {                         \
      floatx4 acc = {0.f, 0.f, 0.f, 0.f};                                      \
      acc = MFMA16(a0, wf[ct][0], acc);                                        \
      acc = MFMA16(a1, wf[ct][1], acc);                                        \
      _Pragma("unroll") for (int r = 0; r < 4; ++r) {                          \
        sum2[ct] += acc[r];                                                    \
        ssq2[ct] += acc[r] * acc[r];                                           \
      }                                                                        \
    }                                                                          \
  }
__global__ void __launch_bounds__(256) k_edge_stats_csr5(
    const unsigned short* __restrict__ il, const unsigned short* __restrict__ jl,
    const __bf16* __restrict__ iP, const __bf16* __restrict__ jP,
    const float* __restrict__ pg1, const float* __restrict__ pbe1,
    const float* __restrict__ cg1, const float* __restrict__ cbe1,
    const float* __restrict__ pW2, const float* __restrict__ cW2,
    float* __restrict__ stats) {
  const int lane = threadIdx.x & 63;
  const int wid = threadIdx.x >> 6;
  const int agg = wid & 1;  // 0 = parent, 1 = child
  const int g = lane >> 4, q = lane & 15;
  const int c8 = lane & 7, e8 = lane >> 3;
  const int c16 = lane & 15;
  const int halfoff = agg * 64;
  const int cbase = c8 * 8;
  __shared__ alignas(16) __bf16 vbuf[4][16 * 72];
  __shared__ float sred[256];
  const float* gg = agg ? cg1 : pg1;
  const float* bb = agg ? cbe1 : pbe1;
  const float* W2 = agg ? cW2 : pW2;
  const int sb2 = agg ? ST_AGG : 0;
  float s1[8], t1[8];
#pragma unroll
  for (int k = 0; k < 8; ++k) {
    int c = cbase + k;
    float mu = stats[sb2 + ST_SUM1 + c] * (1.f / NE);
    float var = (stats[sb2 + ST_SQ1 + c] + 2.f * stats[sb2 + ST_CROSS + c]) * (1.f / NE) - mu * mu;
    float s = gg[c] * rsqrtf(var + BN_EPS);
    s1[k] = s;
    t1[k] = bb[c] - mu * s;
  }
  bf16x8 wf[4][2];
#pragma unroll
  for (int ct = 0; ct < 4; ++ct)
#pragma unroll
    for (int kb = 0; kb < 2; ++kb) wf[ct][kb] = load_wfrag(W2, 64, kb, ct, lane);
  float sum2[4] = {0, 0, 0, 0}, ssq2[4] = {0, 0, 0, 0};
  __bf16* vb = vbuf[wid];
  int wgid = (blockIdx.x * blockDim.x + threadIdx.x) >> 6;
  int nw = (gridDim.x * blockDim.x) >> 6;
  int pw = wgid >> 1;
  int npw = nw >> 1;
  const int NT = NE / 16;
  bf16x8 cA0 = {}, cB0 = {}, cA1 = {}, cB1 = {};
  bf16x8 nA0 = {}, nB0 = {}, nA1 = {}, nB1 = {};
  int ivC = 0, jvC = 0, ivN = 0, jvN = 0;
  int t = pw;
  bool v0 = (t < NT);
  if (v0) {
    ivC = (int)il[t * 16 + c16];
    jvC = (int)jl[t * 16 + c16];
    ES_ISSUE(ivC, jvC, cA0, cB0, cA1, cB1);
    int tn0 = t + npw;
    if (tn0 < NT) { ivN = (int)il[tn0 * 16 + c16]; jvN = (int)jl[tn0 * 16 + c16]; }
  }
  while (v0) {
    int tn = t + npw;
    bool v1 = (tn < NT);
    if (v1) {
      ES_ISSUE(ivN, jvN, nA0, nB0, nA1, nB1);
      int t2 = tn + npw;
      if (t2 < NT) { ivC = (int)il[t2 * 16 + c16]; jvC = (int)jl[t2 * 16 + c16]; }
    }
    ES_COMPUTE(cA0, cB0, cA1, cB1);
    cA0 = nA0; cB0 = nB0; cA1 = nA1; cB1 = nB1;
    { int ti = ivN; ivN = ivC; ivC = ti; ti = jvN; jvN = jvC; jvC = ti; }
    t = tn;
    v0 = v1;
  }
  for (int tt = threadIdx.x; tt < 256; tt += blockDim.x) sred[tt] = 0.f;
  __syncthreads();
  {
    int base = agg * 128;
#pragma unroll
    for (int ct = 0; ct < 4; ++ct) {
      atomicAdd(&sred[base + ct * 16 + q], sum2[ct]);
      atomicAdd(&sred[base + 64 + ct * 16 + q], ssq2[ct]);
    }
  }
  __syncthreads();
  for (int tt = threadIdx.x; tt < 256; tt += blockDim.x) {
    int dstoff;
    if (tt < 64) dstoff = ST_SUM2 + tt;
    else if (tt < 128) dstoff = ST_SSQ2 + (tt - 64);
    else if (tt < 192) dstoff = ST_AGG + ST_SUM2 + (tt - 128);
    else dstoff = ST_AGG + ST_SSQ2 + (tt - 192);
    atomicAdd(&stats[dstoff], sred[tt]);
  }
}

// KE v4 (merged + node-level 2-deep prefetch): blockIdx.y = 0 -> parent
// (dst-CSR -> fi), 1 -> child (src-CSR -> fo). While node n computes, node
// n+nw's (off, A-row, first-tile jl) loads are in flight — removes 2 of the
// 4 serial latencies per node (same mechanism as the stats pipeline win).
__global__ void __launch_bounds__(256) k_scatter_fused(
    const int* __restrict__ off_d, const int* __restrict__ off_s,
    const float* __restrict__ dinv_d, const float* __restrict__ dinv_s,
    const unsigned short* __restrict__ jl_d, const unsigned short* __restrict__ jl_s,
    const __bf16* __restrict__ iP, const __bf16* __restrict__ jP,
    const float* __restrict__ pg1, const float* __restrict__ pbe1,
    const float* __restrict__ cg1, const float* __restrict__ cbe1,
    const float* __restrict__ pg2, const float* __restrict__ pbe2,
    const float* __restrict__ cg2, const float* __restrict__ cbe2,
    const float* __restrict__ pW2, const float* __restrict__ cW2,
    const float* __restrict__ stats, float* __restrict__ fi, float* __restrict__ fo) {
  const int lane = threadIdx.x & 63;
  const int wid = threadIdx.x >> 6;
  const int g = lane >> 4, q = lane & 15;
  const int yy = blockIdx.y;
  const int* off = yy ? off_s : off_d;
  const float* dinv = yy ? dinv_s : dinv_d;
  const unsigned short* jl = yy ? jl_s : jl_d;
  const __bf16* A_ = yy ? (jP + 64) : iP;   // Ac | Ap
  const __bf16* B_ = yy ? (iP + 64) : jP;   // Bc | Bp
  const float* g1 = yy ? cg1 : pg1;
  const float* be1 = yy ? cbe1 : pbe1;
  const float* g2 = yy ? cg2 : pg2;
  const float* be2 = yy ? cbe2 : pbe2;
  const float* W2 = yy ? cW2 : pW2;
  const int sbase = yy ? ST_AGG : 0;
  float* outb = yy ? fo : fi;
  __shared__ alignas(16) __bf16 vbuf[4][16 * 72];
  float s1v[4], t1v[4];
#pragma unroll
  for (int k = 0; k < 4; ++k) {
    int c = 4 * q + k;
    float mu = stats[sbase + ST_SUM1 + c] * (1.f / NE);
    float var = (stats[sbase + ST_SQ1 + c] + 2.f * stats[sbase + ST_CROSS + c]) * (1.f / NE) - mu * mu;
    float s = g1[c] * rsqrtf(var + BN_EPS);
    s1v[k] = s;
    t1v[k] = be1[c] - mu * s;
  }
  float s2v[4], t2v[4];
#pragma unroll
  for (int ct = 0; ct < 4; ++ct) {
    int c = ct * 16 + q;
    float mu = stats[sbase + ST_SUM2 + c] * (1.f / NE);
    float var = stats[sbase + ST_SSQ2 + c] * (1.f / NE) - mu * mu;
    float s = g2[c] * rsqrtf(var + BN_EPS);
    s2v[ct] = s;
    t2v[ct] = be2[c] - mu * s;
  }
  bf16x8 wf[4][2];
#pragma unroll
  for (int ct = 0; ct < 4; ++ct)
#pragma unroll
    for (int kb = 0; kb < 2; ++kb) wf[ct][kb] = load_wfrag(W2, 64, kb, ct, lane);
  __bf16* vb = vbuf[wid];
  int wgid = (blockIdx.x * blockDim.x + threadIdx.x) >> 6;
  int nw = (gridDim.x * blockDim.x) >> 6;
  // --- node-level 2-deep prefetch ---
  int n = wgid;
  int p0 = 0, p1 = 0, jj = 0;
  bf16x4 a4 = {};
  if (n < NN) {
    p0 = off[n];
    p1 = off[n + 1];
    a4 = *(const bf16x4*)(A_ + (size_t)n * 128 + 4 * q);
    int m0 = p1 - p0;
    if (m0 > 16) m0 = 16;
    jj = (lane < m0) ? (int)jl[p0 + lane] : 0;
  }
  while (n < NN) {
    int n2 = n + nw;
    int q0 = 0, q1 = 0, jj2 = 0;
    bf16x4 a42 = {};
    if (n2 < NN) {
      q0 = off[n2];
      q1 = off[n2 + 1];
      a42 = *(const bf16x4*)(A_ + (size_t)n2 * 128 + 4 * q);
      int m0 = q1 - q0;
      if (m0 > 16) m0 = 16;
      jj2 = (lane < m0) ? (int)jl[q0 + lane] : 0;
    }
    float ha[4];
#pragma unroll
    for (int k = 0; k < 4; ++k) ha[k] = (float)a4[k];
    float oacc[4] = {0.f, 0.f, 0.f, 0.f};
    for (int pt = p0; pt < p1; pt += 16) {
      int m = p1 - pt;
      if (m > 16) m = 16;
      int jjt = (pt == p0) ? jj : ((lane < m) ? (int)jl[pt + lane] : 0);
#pragma unroll
      for (int t = 0; t < 4; ++t) {
        int et = t * 4 + g;
        int j = __shfl(jjt, et);
        bf16x4 b4 = *(const bf16x4*)(B_ + (size_t)j * 128 + 4 * q);
        bf16x4 v4;
#pragma unroll
        for (int k = 0; k < 4; ++k)
          v4[k] = (__bf16)fmaxf(s1v[k] * (ha[k] + (float)b4[k]) + t1v[k], 0.f);
        *(bf16x4*)&vb[et * 72 + 4 * q] = v4;
      }
      const bf16x8 a0 = *(const bf16x8*)&vb[q * 72 + g * 8];
      const bf16x8 a1 = *(const bf16x8*)&vb[q * 72 + 32 + g * 8];
#pragma unroll
      for (int ct = 0; ct < 4; ++ct) {
        floatx4 acc = {0.f, 0.f, 0.f, 0.f};
        acc = MFMA16(a0, wf[ct][0], acc);
        acc = MFMA16(a1, wf[ct][1], acc);
#pragma unroll
        for (int r = 0; r < 4; ++r)
          if (g * 4 + r < m) oacc[ct] += fmaxf(s2v[ct] * acc[r] + t2v[ct], 0.f);
      }
    }
#pragma unroll
    for (int ct = 0; ct < 4; ++ct) {
      oacc[ct] += __shfl_xor(oacc[ct], 16);
      oacc[ct] += __shfl_xor(oacc[ct], 32);
    }
    float val = (g == 0) ? oacc[0] : (g == 1) ? oacc[1] : (g == 2) ? oacc[2] : oacc[3];
    outb[(size_t)n * 64 + lane] = dinv[n] * val;
    n = n2;
    p0 = q0;
    p1 = q1;
    jj = jj2;
    a4 = a42;
  }
}

__global__ void __launch_bounds__(256) k_node_update(
    float* __restrict__ x, const float* __restrict__ fi, const float* __restrict__ fo,
    const float* __restrict__ fcW, const float* __restrict__ fcb,
    const float* __restrict__ fc2W, const float* __restrict__ fc2b) {
  const int lane = threadIdx.x & 63;
  const int wid = threadIdx.x >> 6;
  __shared__ alignas(16) __bf16 cat[16 * 200];
  __shared__ alignas(16) __bf16 v2[16 * 136];
  bf16x8 wf1[2][6];
#pragma unroll
  for (int c = 0; c < 2; ++c) {
    int ct = 2 * wid + c;
#pragma unroll
    for (int kb = 0; kb < 6; ++kb) wf1[c][kb] = load_wfrag(fcW, 128, kb, ct, lane);
  }
  bf16x8 wf2[4];
#pragma unroll
  for (int kb = 0; kb < 4; ++kb) wf2[kb] = load_wfrag(fc2W, 64, kb, wid, lane);
  float fcbv[2];
#pragma unroll
  for (int c = 0; c < 2; ++c) fcbv[c] = fcb[(2 * wid + c) * 16 + (lane & 15)];
  float fc2bv = fc2b[wid * 16 + (lane & 15)];

  for (int tile = blockIdx.x; tile < NN / 16; tile += gridDim.x) {
#pragma unroll
    for (int r = 0; r < 4; ++r) {
      int rr = wid * 4 + r;
      int n = tile * 16 + rr;
      cat[rr * 200 + lane] = (__bf16)x[n * 64 + lane];
      cat[rr * 200 + 64 + lane] = (__bf16)fi[n * 64 + lane];
      cat[rr * 200 + 128 + lane] = (__bf16)fo[n * 64 + lane];
    }
    __syncthreads();
    floatx4 acc0 = {0.f, 0.f, 0.f, 0.f}, acc1 = {0.f, 0.f, 0.f, 0.f};
#pragma unroll
    for (int kb = 0; kb < 6; ++kb) {
      bf16x8 af = *(const bf16x8*)&cat[(lane & 15) * 200 + kb * 32 + ((lane >> 4) << 3)];
      acc0 = MFMA16(af, wf1[0][kb], acc0);
      acc1 = MFMA16(af, wf1[1][kb], acc1);
    }
#pragma unroll
    for (int r = 0; r < 4; ++r) {
      int row = ((lane >> 4) << 2) + r;
      v2[row * 136 + (2 * wid) * 16 + (lane & 15)] = (__bf16)fmaxf(acc0[r] + fcbv[0], 0.f);
      v2[row * 136 + (2 * wid + 1) * 16 + (lane & 15)] = (__bf16)fmaxf(acc1[r] + fcbv[1], 0.f);
    }
    __syncthreads();
    floatx4 a2 = {0.f, 0.f, 0.f, 0.f};
#pragma unroll
    for (int kb = 0; kb < 4; ++kb) {
      bf16x8 af = *(const bf16x8*)&v2[(lane & 15) * 136 + kb * 32 + ((lane >> 4) << 3)];
      a2 = MFMA16(af, wf2[kb], a2);
    }
#pragma unroll
    for (int r = 0; r < 4; ++r) {
      int row = ((lane >> 4) << 2) + r;
      int n = tile * 16 + row;
      x[n * 64 + wid * 16 + (lane & 15)] += a2[r] + fc2bv;
    }
    __syncthreads();
  }
}

// KG v2: out = x@convW + convb via MFMA with split-precision x (hi+lo bf16).
__global__ void __launch_bounds__(256) k_conv(const float* __restrict__ x,
                                              const float* __restrict__ convW,
                                              const float* __restrict__ convb,
                                              float* __restrict__ out) {
  const int lane = threadIdx.x & 63;
  const int wid = threadIdx.x >> 6;
  const int q = lane & 15, g = lane >> 4;
  __shared__ alignas(16) __bf16 xh[4][16 * 72];
  __shared__ alignas(16) __bf16 xl[4][16 * 72];
  bf16x8 wf[8][2];
#pragma unroll
  for (int ct = 0; ct < 8; ++ct)
#pragma unroll
    for (int kb = 0; kb < 2; ++kb) wf[ct][kb] = load_wfrag(convW, 128, kb, ct, lane);
  float bv[8];
#pragma unroll
  for (int ct = 0; ct < 8; ++ct) bv[ct] = convb[ct * 16 + q];
  __bf16* vh = xh[wid];
  __bf16* vl = xl[wid];
  int wgid = (blockIdx.x * blockDim.x + threadIdx.x) >> 6;
  int nw = (gridDim.x * blockDim.x) >> 6;
  for (int tile = wgid; tile < NN / 16; tile += nw) {
#pragma unroll
    for (int t = 0; t < 16; ++t) {
      float xv = x[(tile * 16 + t) * 64 + lane];
      __bf16 h = (__bf16)xv;
      vh[t * 72 + lane] = h;
      vl[t * 72 + lane] = (__bf16)(xv - (float)h);
    }
    const bf16x8 h0 = *(const bf16x8*)&vh[q * 72 + (g << 3)];
    const bf16x8 h1 = *(const bf16x8*)&vh[q * 72 + 32 + (g << 3)];
    const bf16x8 l0 = *(const bf16x8*)&vl[q * 72 + (g << 3)];
    const bf16x8 l1 = *(const bf16x8*)&vl[q * 72 + 32 + (g << 3)];
#pragma unroll
    for (int ct = 0; ct < 8; ++ct) {
      floatx4 acc = {0.f, 0.f, 0.f, 0.f};
      acc = MFMA16(l0, wf[ct][0], acc);
      acc = MFMA16(l1, wf[ct][1], acc);
      acc = MFMA16(h0, wf[ct][0], acc);
      acc = MFMA16(h1, wf[ct][1], acc);
#pragma unroll
      for (int r = 0; r < 4; ++r) {
        int row = (g << 2) + r;
        out[(size_t)(tile * 16 + row) * 128 + ct * 16 + q] = acc[r] + bv[ct];
      }
    }
  }
}

extern "C" void kernel_launch(void* const* d_in, const int* in_sizes, int n_in,
                              void* d_out, int out_size, void* d_ws, size_t ws_size,
                              hipStream_t stream) {
  const int* nodes = (const int*)d_in[0];
  const int* edges = (const int*)d_in[1];
  const int* src = edges;
  const int* dst = edges + NE;
  const float* emb = (const float*)d_in[2];
  const float* pW1 = (const float*)d_in[3];
  const float* pg1 = (const float*)d_in[5];
  const float* pbe1 = (const float*)d_in[6];
  const float* pW2 = (const float*)d_in[7];
  const float* pg2 = (const float*)d_in[9];
  const float* pbe2 = (const float*)d_in[10];
  const float* cW1 = (const float*)d_in[11];
  const float* cg1 = (const float*)d_in[13];
  const float* cbe1 = (const float*)d_in[14];
  const float* cW2 = (const float*)d_in[15];
  const float* cg2 = (const float*)d_in[17];
  const float* cbe2 = (const float*)d_in[18];
  const float* fcW = (const float*)d_in[19];
  const float* fcb = (const float*)d_in[20];
  const float* fc2W = (const float*)d_in[21];
  const float* fc2b = (const float*)d_in[22];
  const float* convW = (const float*)d_in[23];
  const float* convb = (const float*)d_in[24];
  float* out = (float*)d_out;

  char* w = (char*)d_ws;
  auto alloc = [&](size_t bytes) {
    char* p = w;
    w += (bytes + 255) & ~(size_t)255;
    return p;
  };
  float* x = (float*)alloc((size_t)NN * 64 * 4);
  __bf16* iP = (__bf16*)alloc((size_t)NN * 128 * 2);  // [Ap | Bc]
  __bf16* jP = (__bf16*)alloc((size_t)NN * 128 * 2);  // [Bp | Ac]
  float* fi = (float*)alloc((size_t)NN * 64 * 4);
  float* fo = (float*)alloc((size_t)NN * 64 * 4);
  unsigned short* jl_d = (unsigned short*)alloc((size_t)NE * 2);
  unsigned short* jl_s = (unsigned short*)alloc((size_t)NE * 2);
  unsigned short* il_d = (unsigned short*)alloc((size_t)NE * 2);
  unsigned short* il_s = (unsigned short*)alloc((size_t)NE * 2);
  int* off_d = (int*)alloc((size_t)(NN + 1) * 4);
  int* off_s = (int*)alloc((size_t)(NN + 1) * 4);
  int* cnt_d = (int*)alloc((size_t)NN * 4);
  int* cnt_s = (int*)alloc((size_t)NN * 4);
  float* dinv_d = (float*)alloc((size_t)NN * 4);
  float* dinv_s = (float*)alloc((size_t)NN * 4);
  float* stats = (float*)alloc(2 * ST_AGG * 4);
  int* btot = (int*)alloc(2 * SCAN_NB * 4);
  int* bcur = (int*)alloc((size_t)2 * NBKT * 4);
  unsigned int* stage = (unsigned int*)alloc((size_t)2 * NBKT * CAP * 4);

  k_setup<<<1024, 256, 0, stream>>>(nodes, emb, x, bcur);
  k_part<<<dim3(NPB, 2), 256, 0, stream>>>(src, dst, bcur, stage);
  k_count<<<dim3(NBKT, 2), 256, 0, stream>>>(bcur, stage, cnt_d, cnt_s);
  k_scan1<<<dim3(SCAN_NB, 2), SCAN_T, 0, stream>>>(cnt_d, cnt_s, off_d, off_s, btot);
  k_scan2<<<1, SCAN_T, 0, stream>>>(btot);
  k_scan3<<<dim3(SCAN_NB, 2), SCAN_T, 0, stream>>>(cnt_d, cnt_s, off_d, off_s, btot,
                                                   dinv_d, dinv_s);
  k_fill2<<<dim3(NBKT, 2), 256, 0, stream>>>(bcur, stage, off_d, off_s, jl_d, jl_s,
                                             il_d, il_s);

  for (int it = 0; it < 2; ++it) {
    // merged parent+child node transform (shared x stream)
    k_node_xform<<<dim3(784, 2), 256, 0, stream>>>(x, pW1, cW1, iP, jP, stats, 1);
    k_node_stats<<<256, 256, 0, stream>>>(iP, jP, cnt_d, cnt_s, stats);
    k_cross_csr3<<<2048, 256, 0, stream>>>(il_d, jl_d, iP, jP, stats);
    k_edge_stats_csr5<<<2048, 256, 0, stream>>>(il_d, jl_d, iP, jP, pg1, pbe1,
                                                cg1, cbe1, pW2, cW2, stats);
    // merged parent+child scatter with node-level prefetch
    k_scatter_fused<<<dim3(2048, 2), 256, 0, stream>>>(
        off_d, off_s, dinv_d, dinv_s, jl_d, jl_s, iP, jP, pg1, pbe1, cg1, cbe1,
        pg2, pbe2, cg2, cbe2, pW2, cW2, stats, fi, fo);
    // Node update
    k_node_update<<<3125, 256, 0, stream>>>(x, fi, fo, fcW, fcb, fc2W, fc2b);
  }
  k_conv<<<784, 256, 0, stream>>>(x, convW, convb, out);
}

// Round 15
// 754.103 us; speedup vs baseline: 1.0190x; 1.0190x over previous
//
#include <hip/hip_runtime.h>

#define NN 50000
#define NE 800000
#define BN_EPS 1e-5f
#define SCAN_T 256
#define SCAN_NB ((NN + SCAN_T - 1) / SCAN_T) // 196

// bucketed CSR build
#define BKT_SH 8                    // 256 nodes per bucket
#define NBKT ((NN + 255) >> 8)      // 196
#define CAP 6144                    // stage capacity per bucket (mean 4096, sd 64)
#define PCH 4096                    // edges per partition block
#define NPB ((NE + PCH - 1) / PCH)  // 196

// stats layout: per-aggregation block of 320 floats; parent at 0, child at 320
#define ST_SUM1 0
#define ST_SQ1 64
#define ST_CROSS 128
#define ST_SUM2 192
#define ST_SSQ2 256
#define ST_AGG 320

using bf16x8 = __attribute__((ext_vector_type(8))) __bf16;
using bf16x4 = __attribute__((ext_vector_type(4))) __bf16;
using floatx4 = __attribute__((ext_vector_type(4))) float;

#define MFMA16(a, b, c) __builtin_amdgcn_mfma_f32_16x16x32_bf16(a, b, c, 0, 0, 0)

// W: row-major [K][ncols] f32. B-frag for 16x16x32: lane holds
// B[k = (lane>>4)*8 + j + kb*32][col = ct*16 + (lane&15)], j=0..7.
__device__ __forceinline__ bf16x8 load_wfrag(const float* W, int ncols, int kb, int ct, int lane) {
  int col = ct * 16 + (lane & 15);
  int k0 = kb * 32 + ((lane >> 4) << 3);
  bf16x8 f;
#pragma unroll
  for (int j = 0; j < 8; ++j) f[j] = (__bf16)W[(k0 + j) * ncols + col];
  return f;
}

// ---------------- setup ----------------
__global__ void k_setup(const int* __restrict__ nodes, const float* __restrict__ emb,
                        float* __restrict__ x, int* __restrict__ bcur) {
  int tid = blockIdx.x * blockDim.x + threadIdx.x;
  int stride = gridDim.x * blockDim.x;
  for (int idx = tid; idx < NN * 64; idx += stride)
    x[idx] = emb[nodes[idx >> 6] * 64 + (idx & 63)];
  for (int t = tid; t < 2 * NBKT; t += stride)
    bcur[t] = (t < NBKT ? t : t - NBKT) * CAP;
}

// Partition edges into node-buckets (256 nodes each). dir 0: key=dst (parent CSR),
// dir 1: key=src (child CSR). Payload packs (key<<16)|other.
__global__ void __launch_bounds__(256) k_part(const int* __restrict__ src,
                                              const int* __restrict__ dst,
                                              int* __restrict__ bcur,
                                              unsigned int* __restrict__ stage) {
  const int dir = blockIdx.y;
  const int* key = dir ? src : dst;
  int* bc = bcur + dir * NBKT;
  unsigned int* st = stage + (size_t)dir * NBKT * CAP;
  __shared__ int lh[256];
  __shared__ int sb[256];
  __shared__ int lbase[NBKT];
  __shared__ unsigned int pay[PCH];
  const int tid = threadIdx.x;
  lh[tid] = 0;
  __syncthreads();
  const int c0 = blockIdx.x * PCH;
  const int nv = (NE - c0 < PCH) ? (NE - c0) : PCH;
  unsigned int rk[PCH / 256];
#pragma unroll
  for (int i = 0; i < PCH / 256; ++i) {
    int l = i * 256 + tid;
    if (l < nv) {
      int b = key[c0 + l] >> BKT_SH;
      int r = atomicAdd(&lh[b], 1);
      rk[i] = ((unsigned)b << 13) | (unsigned)r;
    } else {
      rk[i] = 0xFFFFFFFFu;
    }
  }
  __syncthreads();
  int cntv = lh[tid];
  sb[tid] = cntv;
  __syncthreads();
  for (int o = 1; o < 256; o <<= 1) {
    int u = (tid >= o) ? sb[tid - o] : 0;
    __syncthreads();
    sb[tid] += u;
    __syncthreads();
  }
  int excl = sb[tid] - cntv;
  __syncthreads();
  sb[tid] = excl;
  if (tid < NBKT && cntv > 0) lbase[tid] = atomicAdd(&bc[tid], cntv);
  __syncthreads();
#pragma unroll
  for (int i = 0; i < PCH / 256; ++i) {
    if (rk[i] != 0xFFFFFFFFu) {
      int e = c0 + i * 256 + tid;
      int b = (int)(rk[i] >> 13);
      int r = (int)(rk[i] & 0x1FFFu);
      unsigned int s = (unsigned)src[e], d = (unsigned)dst[e];
      pay[sb[b] + r] = dir ? ((s << 16) | d) : ((d << 16) | s);
    }
  }
  __syncthreads();
  for (int t = tid; t < nv; t += 256) {
    int lo = 0, hi = 255;
    while (lo < hi) {
      int mid = (lo + hi + 1) >> 1;
      if (sb[mid] <= t) lo = mid; else hi = mid - 1;
    }
    st[lbase[lo] + (t - sb[lo])] = pay[t];
  }
}

__global__ void __launch_bounds__(256) k_count(const int* __restrict__ bcur,
                                               const unsigned int* __restrict__ stage,
                                               int* __restrict__ cnt_d, int* __restrict__ cnt_s) {
  const int dir = blockIdx.y;
  const int b = blockIdx.x;
  int* cnt = dir ? cnt_s : cnt_d;
  const unsigned int* st = stage + (size_t)dir * NBKT * CAP + (size_t)b * CAP;
  __shared__ int lc[256];
  lc[threadIdx.x] = 0;
  __syncthreads();
  int sz = bcur[dir * NBKT + b] - b * CAP;
  for (int t = threadIdx.x; t < sz; t += 256)
    atomicAdd(&lc[(st[t] >> 16) - (b << BKT_SH)], 1);
  __syncthreads();
  int n = (b << BKT_SH) + threadIdx.x;
  if (n < NN) cnt[n] = lc[threadIdx.x];
}

__global__ void k_scan1(const int* __restrict__ cnt_d, const int* __restrict__ cnt_s,
                        int* __restrict__ off_d, int* __restrict__ off_s, int* __restrict__ btot) {
  const int* cnt = blockIdx.y ? cnt_s : cnt_d;
  int* off = blockIdx.y ? off_s : off_d;
  __shared__ int sm[SCAN_T];
  int i = blockIdx.x * SCAN_T + threadIdx.x;
  int v = (i < NN) ? cnt[i] : 0;
  sm[threadIdx.x] = v;
  __syncthreads();
  for (int o = 1; o < SCAN_T; o <<= 1) {
    int u = (threadIdx.x >= o) ? sm[threadIdx.x - o] : 0;
    __syncthreads();
    sm[threadIdx.x] += u;
    __syncthreads();
  }
  if (i < NN) off[i] = sm[threadIdx.x];
  if (threadIdx.x == SCAN_T - 1) btot[blockIdx.y * SCAN_NB + blockIdx.x] = sm[SCAN_T - 1];
}

__global__ void k_scan2(int* __restrict__ btot) {
  __shared__ int sm[SCAN_T];
  int t = threadIdx.x;
  for (int y = 0; y < 2; ++y) {
    int v = (t < SCAN_NB) ? btot[y * SCAN_NB + t] : 0;
    sm[t] = v;
    __syncthreads();
    for (int o = 1; o < SCAN_T; o <<= 1) {
      int u = (t >= o) ? sm[t - o] : 0;
      __syncthreads();
      sm[t] += u;
      __syncthreads();
    }
    if (t < SCAN_NB) btot[y * SCAN_NB + t] = sm[t] - v;
    __syncthreads();
  }
}

__global__ void k_scan3(const int* __restrict__ cnt_d, const int* __restrict__ cnt_s,
                        int* __restrict__ off_d, int* __restrict__ off_s,
                        const int* __restrict__ btot, float* __restrict__ dinv_d,
                        float* __restrict__ dinv_s) {
  const int* cnt = blockIdx.y ? cnt_s : cnt_d;
  int* off = blockIdx.y ? off_s : off_d;
  float* dinv = blockIdx.y ? dinv_s : dinv_d;
  int i = blockIdx.x * SCAN_T + threadIdx.x;
  if (i < NN) {
    int incl = off[i];
    int c = cnt[i];
    int o = incl - c + btot[blockIdx.y * SCAN_NB + blockIdx.x];
    off[i] = o;
    dinv[i] = c > 0 ? 1.0f / (float)c : 0.f;
  }
  if (i == NN - 1) off[NN] = NE;
}

// Per-bucket CSR fill; also emits il (the i-node per CSR slot).
__global__ void __launch_bounds__(256) k_fill2(const int* __restrict__ bcur,
                                               const unsigned int* __restrict__ stage,
                                               const int* __restrict__ off_d,
                                               const int* __restrict__ off_s,
                                               unsigned short* __restrict__ jl_d,
                                               unsigned short* __restrict__ jl_s,
                                               unsigned short* __restrict__ il_d,
                                               unsigned short* __restrict__ il_s) {
  const int dir = blockIdx.y;
  const int b = blockIdx.x;
  const int* off = dir ? off_s : off_d;
  unsigned short* jl = dir ? jl_s : jl_d;
  unsigned short* il = dir ? il_s : il_d;
  const unsigned int* st = stage + (size_t)dir * NBKT * CAP + (size_t)b * CAP;
  __shared__ int lcur[256];
  __shared__ unsigned short ljl[CAP];
  __shared__ unsigned short lil[CAP];
  int csr0 = off[b << BKT_SH];
  int n = (b << BKT_SH) + threadIdx.x;
  lcur[threadIdx.x] = (n < NN) ? off[n] - csr0 : 0;
  __syncthreads();
  int sz = bcur[dir * NBKT + b] - b * CAP;
  for (int t = threadIdx.x; t < sz; t += 256) {
    unsigned int v = st[t];
    int p = atomicAdd(&lcur[(v >> 16) - (b << BKT_SH)], 1);
    ljl[p] = (unsigned short)(v & 0xFFFFu);
    lil[p] = (unsigned short)(v >> 16);
  }
  __syncthreads();
  for (int t = threadIdx.x; t < sz; t += 256) {
    jl[csr0 + t] = ljl[t];
    il[csr0 + t] = lil[t];
  }
}

// ---------------- per-iteration kernels ----------------
// KA (merged): blockIdx.y = 0 -> parent (pW1: A->iP lo, B->jP lo, do_zero),
//              blockIdx.y = 1 -> child  (cW1: A->jP hi, B->iP hi).
__global__ void __launch_bounds__(256) k_node_xform(
    const float* __restrict__ x, const float* __restrict__ pW1,
    const float* __restrict__ cW1, __bf16* __restrict__ iP, __bf16* __restrict__ jP,
    float* __restrict__ stats, int do_zero) {
  const int lane = threadIdx.x & 63;
  const int wid = threadIdx.x >> 6;
  const int yy = blockIdx.y;
  const float* W1 = yy ? cW1 : pW1;
  __bf16* Aout = yy ? (jP + 64) : iP;
  __bf16* Bout = yy ? (iP + 64) : jP;
  __shared__ alignas(16) __bf16 xb[4][16 * 72];
  if (do_zero && blockIdx.x == 0 && yy == 0)
    for (int t = threadIdx.x; t < 2 * ST_AGG; t += blockDim.x) stats[t] = 0.f;
  bf16x8 wfa[4][2], wfb[4][2];
#pragma unroll
  for (int ct = 0; ct < 4; ++ct)
#pragma unroll
    for (int kb = 0; kb < 2; ++kb) {
      wfa[ct][kb] = load_wfrag(W1, 64, kb, ct, lane);
      wfb[ct][kb] = load_wfrag(W1 + 64 * 64, 64, kb, ct, lane);
    }
  __bf16* vb = xb[wid];
  int wgid = (blockIdx.x * blockDim.x + threadIdx.x) >> 6;
  int nw = (gridDim.x * blockDim.x) >> 6;
  for (int tile = wgid; tile < NN / 16; tile += nw) {
#pragma unroll
    for (int t = 0; t < 16; ++t)
      vb[t * 72 + lane] = (__bf16)x[(tile * 16 + t) * 64 + lane];
    const bf16x8 a0 = *(const bf16x8*)&vb[(lane & 15) * 72 + ((lane >> 4) << 3)];
    const bf16x8 a1 = *(const bf16x8*)&vb[(lane & 15) * 72 + 32 + ((lane >> 4) << 3)];
#pragma unroll
    for (int ct = 0; ct < 4; ++ct) {
      floatx4 aA = {0.f, 0.f, 0.f, 0.f}, aB = {0.f, 0.f, 0.f, 0.f};
      aA = MFMA16(a0, wfa[ct][0], aA);
      aA = MFMA16(a1, wfa[ct][1], aA);
      aB = MFMA16(a0, wfb[ct][0], aB);
      aB = MFMA16(a1, wfb[ct][1], aB);
#pragma unroll
      for (int r = 0; r < 4; ++r) {
        int row = ((lane >> 4) << 2) + r;
        int n = tile * 16 + row;
        int col = ct * 16 + (lane & 15);
        Aout[(size_t)n * 128 + col] = (__bf16)aA[r];
        Bout[(size_t)n * 128 + col] = (__bf16)aB[r];
      }
    }
  }
}

// KB: degree-weighted node sums over interleaved iP/jP.
__global__ void __launch_bounds__(256) k_node_stats(
    const __bf16* __restrict__ iP, const __bf16* __restrict__ jP,
    const int* __restrict__ cnt_d, const int* __restrict__ cnt_s,
    float* __restrict__ stats) {
  const int lane = threadIdx.x & 63;
  const int g = lane >> 4, q = lane & 15;
  __shared__ float sacc[256];
  for (int t = threadIdx.x; t < 256; t += blockDim.x) sacc[t] = 0.f;
  __syncthreads();
  float sp[4] = {0, 0, 0, 0}, qp[4] = {0, 0, 0, 0};
  float sc[4] = {0, 0, 0, 0}, qc[4] = {0, 0, 0, 0};
  int wgid = (blockIdx.x * blockDim.x + threadIdx.x) >> 6;
  int nw = (gridDim.x * blockDim.x) >> 6;
  for (int ch = wgid; ch < NN / 4; ch += nw) {
    int n = ch * 4 + g;
    float wd = (float)cnt_d[n];
    float ws = (float)cnt_s[n];
    bf16x4 ap = *(const bf16x4*)(iP + (size_t)n * 128 + 4 * q);
    bf16x4 bp = *(const bf16x4*)(jP + (size_t)n * 128 + 4 * q);
    bf16x4 ac = *(const bf16x4*)(jP + (size_t)n * 128 + 64 + 4 * q);
    bf16x4 bc = *(const bf16x4*)(iP + (size_t)n * 128 + 64 + 4 * q);
#pragma unroll
    for (int k = 0; k < 4; ++k) {
      float a = (float)ap[k], b = (float)bp[k], c = (float)ac[k], d = (float)bc[k];
      sp[k] += wd * a + ws * b;
      qp[k] += wd * a * a + ws * b * b;
      sc[k] += ws * c + wd * d;
      qc[k] += ws * c * c + wd * d * d;
    }
  }
#pragma unroll
  for (int k = 0; k < 4; ++k) {
    sp[k] += __shfl_xor(sp[k], 16); sp[k] += __shfl_xor(sp[k], 32);
    qp[k] += __shfl_xor(qp[k], 16); qp[k] += __shfl_xor(qp[k], 32);
    sc[k] += __shfl_xor(sc[k], 16); sc[k] += __shfl_xor(sc[k], 32);
    qc[k] += __shfl_xor(qc[k], 16); qc[k] += __shfl_xor(qc[k], 32);
  }
  if (lane < 16) {
#pragma unroll
    for (int k = 0; k < 4; ++k) {
      atomicAdd(&sacc[4 * q + k], sp[k]);
      atomicAdd(&sacc[64 + 4 * q + k], qp[k]);
      atomicAdd(&sacc[128 + 4 * q + k], sc[k]);
      atomicAdd(&sacc[192 + 4 * q + k], qc[k]);
    }
  }
  __syncthreads();
  for (int t = threadIdx.x; t < 256; t += blockDim.x) {
    int dstoff = (t < 128) ? t : ST_AGG + (t - 128);
    atomicAdd(&stats[dstoff], sacc[t]);
  }
}

// KC v4: cross over dst-CSR positions with interleaved rows (verified R9 form).
__global__ void __launch_bounds__(256) k_cross_csr3(
    const unsigned short* __restrict__ il, const unsigned short* __restrict__ jl,
    const __bf16* __restrict__ iP, const __bf16* __restrict__ jP,
    float* __restrict__ stats) {
  const int lane = threadIdx.x & 63;
  const int c16 = lane & 15, r4 = lane >> 4;
  __shared__ float sacc[128];
  for (int t = threadIdx.x; t < 128; t += blockDim.x) sacc[t] = 0.f;
  __syncthreads();
  float acc[8] = {0, 0, 0, 0, 0, 0, 0, 0};
  int wgid = (blockIdx.x * blockDim.x + threadIdx.x) >> 6;
  int nw = (gridDim.x * blockDim.x) >> 6;
  for (int tile = wgid; tile < NE / 16; tile += nw) {
    int e0 = tile * 16;
    int iv = (int)il[e0 + c16];
    int jv = (int)jl[e0 + c16];
#pragma unroll
    for (int r = 0; r < 4; ++r) {
      int ee = r * 4 + r4;
      int i = __shfl(iv, ee);
      int j = __shfl(jv, ee);
      bf16x8 av = *(const bf16x8*)(iP + (size_t)i * 128 + c16 * 8);
      bf16x8 bv = *(const bf16x8*)(jP + (size_t)j * 128 + c16 * 8);
#pragma unroll
      for (int k = 0; k < 8; ++k) acc[k] += (float)av[k] * (float)bv[k];
    }
  }
#pragma unroll
  for (int k = 0; k < 8; ++k) {
    acc[k] += __shfl_xor(acc[k], 16);
    acc[k] += __shfl_xor(acc[k], 32);
  }
  if (lane < 16) {
#pragma unroll
    for (int k = 0; k < 8; ++k) {
      int dst = (c16 < 8) ? (c16 * 8 + k) : (64 + (c16 - 8) * 8 + k);
      atomicAdd(&sacc[dst], acc[k]);
    }
  }
  __syncthreads();
  for (int t = threadIdx.x; t < 128; t += blockDim.x) {
    int dstoff = (t < 64) ? (ST_CROSS + t) : (ST_AGG + ST_CROSS + (t - 64));
    atomicAdd(&stats[dstoff], sacc[t]);
  }
}

// KD v7: BN2 stats, wave-split by aggregation + 2-deep software pipeline
// (verified R13 form).
#define ES_ISSUE(iv, jv, r0a, r0b, r1a, r1b)                                   \
  {                                                                            \
    int i0 = __shfl((iv), e8), j0 = __shfl((jv), e8);                          \
    int i1 = __shfl((iv), 8 + e8), j1 = __shfl((jv), 8 + e8);                  \
    r0a = *(const bf16x8*)(iP + (size_t)i0 * 128 + halfoff + cbase);           \
    r0b = *(const bf16x8*)(jP + (size_t)j0 * 128 + halfoff + cbase);           \
    r1a = *(const bf16x8*)(iP + (size_t)i1 * 128 + halfoff + cbase);           \
    r1b = *(const bf16x8*)(jP + (size_t)j1 * 128 + halfoff + cbase);           \
  }
#define ES_COMPUTE(r0a, r0b, r1a, r1b)                                         \
  {                                                                            \
    bf16x8 v0, v1;                                                             \
    _Pragma("unroll") for (int k = 0; k < 8; ++k) {                            \
      v0[k] = (__bf16)fmaxf(s1[k] * ((float)r0a[k] + (float)r0b[k]) + t1[k], 0.f); \
      v1[k] = (__bf16)fmaxf(s1[k] * ((float)r1a[k] + (float)r1b[k]) + t1[k], 0.f); \
    }                                                                          \
    *(bf16x8*)&vb[e8 * 72 + cbase] = v0;                                       \
    *(bf16x8*)&vb[(8 + e8) * 72 + cbase] = v1;                                 \
    const bf16x8 a0 = *(const bf16x8*)&vb[q * 72 + g * 8];                     \
    const bf16x8 a1 = *(const bf16x8*)&vb[q * 72 + 32 + g * 8];                \
    _Pragma("unroll") for (int ct = 0; ct < 4; ++ct) {                         \
      floatx4 acc = {0.f, 0.f, 0.f, 0.f};                                      \
      acc = MFMA16(a0, wf[ct][0], acc);                                        \
      acc = MFMA16(a1, wf[ct][1], acc);                                        \
      _Pragma("unroll") for (int r = 0; r < 4; ++r) {                          \
        sum2[ct] += acc[r];                                                    \
        ssq2[ct] += acc[r] * acc[r];                                           \
      }                                                                        \
    }                                                                          \
  }
__global__ void __launch_bounds__(256) k_edge_stats_csr5(
    const unsigned short* __restrict__ il, const unsigned short* __restrict__ jl,
    const __bf16* __restrict__ iP, const __bf16* __restrict__ jP,
    const float* __restrict__ pg1, const float* __restrict__ pbe1,
    const float* __restrict__ cg1, const float* __restrict__ cbe1,
    const float* __restrict__ pW2, const float* __restrict__ cW2,
    float* __restrict__ stats) {
  const int lane = threadIdx.x & 63;
  const int wid = threadIdx.x >> 6;
  const int agg = wid & 1;  // 0 = parent, 1 = child
  const int g = lane >> 4, q = lane & 15;
  const int c8 = lane & 7, e8 = lane >> 3;
  const int c16 = lane & 15;
  const int halfoff = agg * 64;
  const int cbase = c8 * 8;
  __shared__ alignas(16) __bf16 vbuf[4][16 * 72];
  __shared__ float sred[256];
  const float* gg = agg ? cg1 : pg1;
  const float* bb = agg ? cbe1 : pbe1;
  const float* W2 = agg ? cW2 : pW2;
  const int sb2 = agg ? ST_AGG : 0;
  float s1[8], t1[8];
#pragma unroll
  for (int k = 0; k < 8; ++k) {
    int c = cbase + k;
    float mu = stats[sb2 + ST_SUM1 + c] * (1.f / NE);
    float var = (stats[sb2 + ST_SQ1 + c] + 2.f * stats[sb2 + ST_CROSS + c]) * (1.f / NE) - mu * mu;
    float s = gg[c] * rsqrtf(var + BN_EPS);
    s1[k] = s;
    t1[k] = bb[c] - mu * s;
  }
  bf16x8 wf[4][2];
#pragma unroll
  for (int ct = 0; ct < 4; ++ct)
#pragma unroll
    for (int kb = 0; kb < 2; ++kb) wf[ct][kb] = load_wfrag(W2, 64, kb, ct, lane);
  float sum2[4] = {0, 0, 0, 0}, ssq2[4] = {0, 0, 0, 0};
  __bf16* vb = vbuf[wid];
  int wgid = (blockIdx.x * blockDim.x + threadIdx.x) >> 6;
  int nw = (gridDim.x * blockDim.x) >> 6;
  int pw = wgid >> 1;
  int npw = nw >> 1;
  const int NT = NE / 16;
  bf16x8 cA0 = {}, cB0 = {}, cA1 = {}, cB1 = {};
  bf16x8 nA0 = {}, nB0 = {}, nA1 = {}, nB1 = {};
  int ivC = 0, jvC = 0, ivN = 0, jvN = 0;
  int t = pw;
  bool v0 = (t < NT);
  if (v0) {
    ivC = (int)il[t * 16 + c16];
    jvC = (int)jl[t * 16 + c16];
    ES_ISSUE(ivC, jvC, cA0, cB0, cA1, cB1);
    int tn0 = t + npw;
    if (tn0 < NT) { ivN = (int)il[tn0 * 16 + c16]; jvN = (int)jl[tn0 * 16 + c16]; }
  }
  while (v0) {
    int tn = t + npw;
    bool v1 = (tn < NT);
    if (v1) {
      ES_ISSUE(ivN, jvN, nA0, nB0, nA1, nB1);
      int t2 = tn + npw;
      if (t2 < NT) { ivC = (int)il[t2 * 16 + c16]; jvC = (int)jl[t2 * 16 + c16]; }
    }
    ES_COMPUTE(cA0, cB0, cA1, cB1);
    cA0 = nA0; cB0 = nB0; cA1 = nA1; cB1 = nB1;
    { int ti = ivN; ivN = ivC; ivC = ti; ti = jvN; jvN = jvC; jvC = ti; }
    t = tn;
    v0 = v1;
  }
  for (int tt = threadIdx.x; tt < 256; tt += blockDim.x) sred[tt] = 0.f;
  __syncthreads();
  {
    int base = agg * 128;
#pragma unroll
    for (int ct = 0; ct < 4; ++ct) {
      atomicAdd(&sred[base + ct * 16 + q], sum2[ct]);
      atomicAdd(&sred[base + 64 + ct * 16 + q], ssq2[ct]);
    }
  }
  __syncthreads();
  for (int tt = threadIdx.x; tt < 256; tt += blockDim.x) {
    int dstoff;
    if (tt < 64) dstoff = ST_SUM2 + tt;
    else if (tt < 128) dstoff = ST_SSQ2 + (tt - 64);
    else if (tt < 192) dstoff = ST_AGG + ST_SUM2 + (tt - 128);
    else dstoff = ST_AGG + ST_SSQ2 + (tt - 192);
    atomicAdd(&stats[dstoff], sred[tt]);
  }
}

// KE (merged, verified R10 body): blockIdx.y = 0 -> parent (dst-CSR -> fi),
// blockIdx.y = 1 -> child (src-CSR -> fo). No node-prefetch (R14 falsified it:
// +8 VGPR cut occupancy 36->27% and cost +7 us).
__global__ void __launch_bounds__(256) k_scatter_fused(
    const int* __restrict__ off_d, const int* __restrict__ off_s,
    const float* __restrict__ dinv_d, const float* __restrict__ dinv_s,
    const unsigned short* __restrict__ jl_d, const unsigned short* __restrict__ jl_s,
    const __bf16* __restrict__ iP, const __bf16* __restrict__ jP,
    const float* __restrict__ pg1, const float* __restrict__ pbe1,
    const float* __restrict__ cg1, const float* __restrict__ cbe1,
    const float* __restrict__ pg2, const float* __restrict__ pbe2,
    const float* __restrict__ cg2, const float* __restrict__ cbe2,
    const float* __restrict__ pW2, const float* __restrict__ cW2,
    const float* __restrict__ stats, float* __restrict__ fi, float* __restrict__ fo) {
  const int lane = threadIdx.x & 63;
  const int wid = threadIdx.x >> 6;
  const int g = lane >> 4, q = lane & 15;
  const int yy = blockIdx.y;
  const int* off = yy ? off_s : off_d;
  const float* dinv = yy ? dinv_s : dinv_d;
  const unsigned short* jl = yy ? jl_s : jl_d;
  const __bf16* A_ = yy ? (jP + 64) : iP;   // Ac | Ap
  const __bf16* B_ = yy ? (iP + 64) : jP;   // Bc | Bp
  const float* g1 = yy ? cg1 : pg1;
  const float* be1 = yy ? cbe1 : pbe1;
  const float* g2 = yy ? cg2 : pg2;
  const float* be2 = yy ? cbe2 : pbe2;
  const float* W2 = yy ? cW2 : pW2;
  const int sbase = yy ? ST_AGG : 0;
  float* outb = yy ? fo : fi;
  __shared__ alignas(16) __bf16 vbuf[4][16 * 72];
  float s1v[4], t1v[4];
#pragma unroll
  for (int k = 0; k < 4; ++k) {
    int c = 4 * q + k;
    float mu = stats[sbase + ST_SUM1 + c] * (1.f / NE);
    float var = (stats[sbase + ST_SQ1 + c] + 2.f * stats[sbase + ST_CROSS + c]) * (1.f / NE) - mu * mu;
    float s = g1[c] * rsqrtf(var + BN_EPS);
    s1v[k] = s;
    t1v[k] = be1[c] - mu * s;
  }
  float s2v[4], t2v[4];
#pragma unroll
  for (int ct = 0; ct < 4; ++ct) {
    int c = ct * 16 + q;
    float mu = stats[sbase + ST_SUM2 + c] * (1.f / NE);
    float var = stats[sbase + ST_SSQ2 + c] * (1.f / NE) - mu * mu;
    float s = g2[c] * rsqrtf(var + BN_EPS);
    s2v[ct] = s;
    t2v[ct] = be2[c] - mu * s;
  }
  bf16x8 wf[4][2];
#pragma unroll
  for (int ct = 0; ct < 4; ++ct)
#pragma unroll
    for (int kb = 0; kb < 2; ++kb) wf[ct][kb] = load_wfrag(W2, 64, kb, ct, lane);
  __bf16* vb = vbuf[wid];
  int wgid = (blockIdx.x * blockDim.x + threadIdx.x) >> 6;
  int nw = (gridDim.x * blockDim.x) >> 6;
  for (int n = wgid; n < NN; n += nw) {
    int p0 = off[n], p1 = off[n + 1];
    bf16x4 a4 = *(const bf16x4*)(A_ + (size_t)n * 128 + 4 * q);
    float ha[4];
#pragma unroll
    for (int k = 0; k < 4; ++k) ha[k] = (float)a4[k];
    float oacc[4] = {0.f, 0.f, 0.f, 0.f};
    for (int pt = p0; pt < p1; pt += 16) {
      int m = p1 - pt;
      if (m > 16) m = 16;
      int jj = (lane < m) ? (int)jl[pt + lane] : 0;
#pragma unroll
      for (int t = 0; t < 4; ++t) {
        int et = t * 4 + g;
        int j = __shfl(jj, et);
        bf16x4 b4 = *(const bf16x4*)(B_ + (size_t)j * 128 + 4 * q);
        bf16x4 v4;
#pragma unroll
        for (int k = 0; k < 4; ++k)
          v4[k] = (__bf16)fmaxf(s1v[k] * (ha[k] + (float)b4[k]) + t1v[k], 0.f);
        *(bf16x4*)&vb[et * 72 + 4 * q] = v4;
      }
      const bf16x8 a0 = *(const bf16x8*)&vb[q * 72 + g * 8];
      const bf16x8 a1 = *(const bf16x8*)&vb[q * 72 + 32 + g * 8];
#pragma unroll
      for (int ct = 0; ct < 4; ++ct) {
        floatx4 acc = {0.f, 0.f, 0.f, 0.f};
        acc = MFMA16(a0, wf[ct][0], acc);
        acc = MFMA16(a1, wf[ct][1], acc);
#pragma unroll
        for (int r = 0; r < 4; ++r)
          if (g * 4 + r < m) oacc[ct] += fmaxf(s2v[ct] * acc[r] + t2v[ct], 0.f);
      }
    }
#pragma unroll
    for (int ct = 0; ct < 4; ++ct) {
      oacc[ct] += __shfl_xor(oacc[ct], 16);
      oacc[ct] += __shfl_xor(oacc[ct], 32);
    }
    float val = (g == 0) ? oacc[0] : (g == 1) ? oacc[1] : (g == 2) ? oacc[2] : oacc[3];
    outb[(size_t)n * 64 + lane] = dinv[n] * val;
  }
}

__global__ void __launch_bounds__(256) k_node_update(
    float* __restrict__ x, const float* __restrict__ fi, const float* __restrict__ fo,
    const float* __restrict__ fcW, const float* __restrict__ fcb,
    const float* __restrict__ fc2W, const float* __restrict__ fc2b) {
  const int lane = threadIdx.x & 63;
  const int wid = threadIdx.x >> 6;
  __shared__ alignas(16) __bf16 cat[16 * 200];
  __shared__ alignas(16) __bf16 v2[16 * 136];
  bf16x8 wf1[2][6];
#pragma unroll
  for (int c = 0; c < 2; ++c) {
    int ct = 2 * wid + c;
#pragma unroll
    for (int kb = 0; kb < 6; ++kb) wf1[c][kb] = load_wfrag(fcW, 128, kb, ct, lane);
  }
  bf16x8 wf2[4];
#pragma unroll
  for (int kb = 0; kb < 4; ++kb) wf2[kb] = load_wfrag(fc2W, 64, kb, wid, lane);
  float fcbv[2];
#pragma unroll
  for (int c = 0; c < 2; ++c) fcbv[c] = fcb[(2 * wid + c) * 16 + (lane & 15)];
  float fc2bv = fc2b[wid * 16 + (lane & 15)];

  for (int tile = blockIdx.x; tile < NN / 16; tile += gridDim.x) {
#pragma unroll
    for (int r = 0; r < 4; ++r) {
      int rr = wid * 4 + r;
      int n = tile * 16 + rr;
      cat[rr * 200 + lane] = (__bf16)x[n * 64 + lane];
      cat[rr * 200 + 64 + lane] = (__bf16)fi[n * 64 + lane];
      cat[rr * 200 + 128 + lane] = (__bf16)fo[n * 64 + lane];
    }
    __syncthreads();
    floatx4 acc0 = {0.f, 0.f, 0.f, 0.f}, acc1 = {0.f, 0.f, 0.f, 0.f};
#pragma unroll
    for (int kb = 0; kb < 6; ++kb) {
      bf16x8 af = *(const bf16x8*)&cat[(lane & 15) * 200 + kb * 32 + ((lane >> 4) << 3)];
      acc0 = MFMA16(af, wf1[0][kb], acc0);
      acc1 = MFMA16(af, wf1[1][kb], acc1);
    }
#pragma unroll
    for (int r = 0; r < 4; ++r) {
      int row = ((lane >> 4) << 2) + r;
      v2[row * 136 + (2 * wid) * 16 + (lane & 15)] = (__bf16)fmaxf(acc0[r] + fcbv[0], 0.f);
      v2[row * 136 + (2 * wid + 1) * 16 + (lane & 15)] = (__bf16)fmaxf(acc1[r] + fcbv[1], 0.f);
    }
    __syncthreads();
    floatx4 a2 = {0.f, 0.f, 0.f, 0.f};
#pragma unroll
    for (int kb = 0; kb < 4; ++kb) {
      bf16x8 af = *(const bf16x8*)&v2[(lane & 15) * 136 + kb * 32 + ((lane >> 4) << 3)];
      a2 = MFMA16(af, wf2[kb], a2);
    }
#pragma unroll
    for (int r = 0; r < 4; ++r) {
      int row = ((lane >> 4) << 2) + r;
      int n = tile * 16 + row;
      x[n * 64 + wid * 16 + (lane & 15)] += a2[r] + fc2bv;
    }
    __syncthreads();
  }
}

// KG v2: out = x@convW + convb via MFMA with split-precision x (hi+lo bf16).
__global__ void __launch_bounds__(256) k_conv(const float* __restrict__ x,
                                              const float* __restrict__ convW,
                                              const float* __restrict__ convb,
                                              float* __restrict__ out) {
  const int lane = threadIdx.x & 63;
  const int wid = threadIdx.x >> 6;
  const int q = lane & 15, g = lane >> 4;
  __shared__ alignas(16) __bf16 xh[4][16 * 72];
  __shared__ alignas(16) __bf16 xl[4][16 * 72];
  bf16x8 wf[8][2];
#pragma unroll
  for (int ct = 0; ct < 8; ++ct)
#pragma unroll
    for (int kb = 0; kb < 2; ++kb) wf[ct][kb] = load_wfrag(convW, 128, kb, ct, lane);
  float bv[8];
#pragma unroll
  for (int ct = 0; ct < 8; ++ct) bv[ct] = convb[ct * 16 + q];
  __bf16* vh = xh[wid];
  __bf16* vl = xl[wid];
  int wgid = (blockIdx.x * blockDim.x + threadIdx.x) >> 6;
  int nw = (gridDim.x * blockDim.x) >> 6;
  for (int tile = wgid; tile < NN / 16; tile += nw) {
#pragma unroll
    for (int t = 0; t < 16; ++t) {
      float xv = x[(tile * 16 + t) * 64 + lane];
      __bf16 h = (__bf16)xv;
      vh[t * 72 + lane] = h;
      vl[t * 72 + lane] = (__bf16)(xv - (float)h);
    }
    const bf16x8 h0 = *(const bf16x8*)&vh[q * 72 + (g << 3)];
    const bf16x8 h1 = *(const bf16x8*)&vh[q * 72 + 32 + (g << 3)];
    const bf16x8 l0 = *(const bf16x8*)&vl[q * 72 + (g << 3)];
    const bf16x8 l1 = *(const bf16x8*)&vl[q * 72 + 32 + (g << 3)];
#pragma unroll
    for (int ct = 0; ct < 8; ++ct) {
      floatx4 acc = {0.f, 0.f, 0.f, 0.f};
      acc = MFMA16(l0, wf[ct][0], acc);
      acc = MFMA16(l1, wf[ct][1], acc);
      acc = MFMA16(h0, wf[ct][0], acc);
      acc = MFMA16(h1, wf[ct][1], acc);
#pragma unroll
      for (int r = 0; r < 4; ++r) {
        int row = (g << 2) + r;
        out[(size_t)(tile * 16 + row) * 128 + ct * 16 + q] = acc[r] + bv[ct];
      }
    }
  }
}

extern "C" void kernel_launch(void* const* d_in, const int* in_sizes, int n_in,
                              void* d_out, int out_size, void* d_ws, size_t ws_size,
                              hipStream_t stream) {
  const int* nodes = (const int*)d_in[0];
  const int* edges = (const int*)d_in[1];
  const int* src = edges;
  const int* dst = edges + NE;
  const float* emb = (const float*)d_in[2];
  const float* pW1 = (const float*)d_in[3];
  const float* pg1 = (const float*)d_in[5];
  const float* pbe1 = (const float*)d_in[6];
  const float* pW2 = (const float*)d_in[7];
  const float* pg2 = (const float*)d_in[9];
  const float* pbe2 = (const float*)d_in[10];
  const float* cW1 = (const float*)d_in[11];
  const float* cg1 = (const float*)d_in[13];
  const float* cbe1 = (const float*)d_in[14];
  const float* cW2 = (const float*)d_in[15];
  const float* cg2 = (const float*)d_in[17];
  const float* cbe2 = (const float*)d_in[18];
  const float* fcW = (const float*)d_in[19];
  const float* fcb = (const float*)d_in[20];
  const float* fc2W = (const float*)d_in[21];
  const float* fc2b = (const float*)d_in[22];
  const float* convW = (const float*)d_in[23];
  const float* convb = (const float*)d_in[24];
  float* out = (float*)d_out;

  char* w = (char*)d_ws;
  auto alloc = [&](size_t bytes) {
    char* p = w;
    w += (bytes + 255) & ~(size_t)255;
    return p;
  };
  float* x = (float*)alloc((size_t)NN * 64 * 4);
  __bf16* iP = (__bf16*)alloc((size_t)NN * 128 * 2);  // [Ap | Bc]
  __bf16* jP = (__bf16*)alloc((size_t)NN * 128 * 2);  // [Bp | Ac]
  float* fi = (float*)alloc((size_t)NN * 64 * 4);
  float* fo = (float*)alloc((size_t)NN * 64 * 4);
  unsigned short* jl_d = (unsigned short*)alloc((size_t)NE * 2);
  unsigned short* jl_s = (unsigned short*)alloc((size_t)NE * 2);
  unsigned short* il_d = (unsigned short*)alloc((size_t)NE * 2);
  unsigned short* il_s = (unsigned short*)alloc((size_t)NE * 2);
  int* off_d = (int*)alloc((size_t)(NN + 1) * 4);
  int* off_s = (int*)alloc((size_t)(NN + 1) * 4);
  int* cnt_d = (int*)alloc((size_t)NN * 4);
  int* cnt_s = (int*)alloc((size_t)NN * 4);
  float* dinv_d = (float*)alloc((size_t)NN * 4);
  float* dinv_s = (float*)alloc((size_t)NN * 4);
  float* stats = (float*)alloc(2 * ST_AGG * 4);
  int* btot = (int*)alloc(2 * SCAN_NB * 4);
  int* bcur = (int*)alloc((size_t)2 * NBKT * 4);
  unsigned int* stage = (unsigned int*)alloc((size_t)2 * NBKT * CAP * 4);

  k_setup<<<1024, 256, 0, stream>>>(nodes, emb, x, bcur);
  k_part<<<dim3(NPB, 2), 256, 0, stream>>>(src, dst, bcur, stage);
  k_count<<<dim3(NBKT, 2), 256, 0, stream>>>(bcur, stage, cnt_d, cnt_s);
  k_scan1<<<dim3(SCAN_NB, 2), SCAN_T, 0, stream>>>(cnt_d, cnt_s, off_d, off_s, btot);
  k_scan2<<<1, SCAN_T, 0, stream>>>(btot);
  k_scan3<<<dim3(SCAN_NB, 2), SCAN_T, 0, stream>>>(cnt_d, cnt_s, off_d, off_s, btot,
                                                   dinv_d, dinv_s);
  k_fill2<<<dim3(NBKT, 2), 256, 0, stream>>>(bcur, stage, off_d, off_s, jl_d, jl_s,
                                             il_d, il_s);

  for (int it = 0; it < 2; ++it) {
    // merged parent+child node transform (shared x stream)
    k_node_xform<<<dim3(784, 2), 256, 0, stream>>>(x, pW1, cW1, iP, jP, stats, 1);
    k_node_stats<<<256, 256, 0, stream>>>(iP, jP, cnt_d, cnt_s, stats);
    k_cross_csr3<<<2048, 256, 0, stream>>>(il_d, jl_d, iP, jP, stats);
    k_edge_stats_csr5<<<2048, 256, 0, stream>>>(il_d, jl_d, iP, jP, pg1, pbe1,
                                                cg1, cbe1, pW2, cW2, stats);
    // merged parent+child scatter
    k_scatter_fused<<<dim3(2048, 2), 256, 0, stream>>>(
        off_d, off_s, dinv_d, dinv_s, jl_d, jl_s, iP, jP, pg1, pbe1, cg1, cbe1,
        pg2, pbe2, cg2, cbe2, pW2, cW2, stats, fi, fo);
    // Node update
    k_node_update<<<3125, 256, 0, stream>>>(x, fi, fo, fcW, fcb, fc2W, fc2b);
  }
  k_conv<<<784, 256, 0, stream>>>(x, convW, convb, out);
}